// Round 11
// baseline (355.843 us; speedup 1.0000x reference)
//
#include <hip/hip_runtime.h>

// ---------- common helpers ----------
typedef short bf16x8 __attribute__((ext_vector_type(8)));
typedef float f32x4 __attribute__((ext_vector_type(4)));

__device__ __forceinline__ void async16(const void* g, const void* l) {
  __builtin_amdgcn_global_load_lds(
      (const __attribute__((address_space(1))) unsigned int*)g,
      (__attribute__((address_space(3))) unsigned int*)(void*)(uintptr_t)l,
      16, 0, 0);
}

__device__ __forceinline__ unsigned short f2b(float f) {
  unsigned int u = __float_as_uint(f);
  u += 0x7fffu + ((u >> 16) & 1u);   // round-to-nearest-even
  return (unsigned short)(u >> 16);
}

// ---------- fused prep: cast x + all 5 weight transposes, ONE launch ----------
__device__ __forceinline__ void transpose_tile(
    const float* __restrict__ in, unsigned short* __restrict__ out,
    int K, int N, int bx, int by, unsigned short (*tile)[65]) {
  const int k0 = by * 64, n0 = bx * 64;
  const int tid = threadIdx.x;
  const int r = tid >> 4, c4 = tid & 15;
#pragma unroll
  for (int p = 0; p < 4; ++p) {
    int row = p * 16 + r;
    float4 v = *(const float4*)(in + (size_t)(k0 + row) * N + n0 + c4 * 4);
    tile[c4 * 4 + 0][row] = f2b(v.x);
    tile[c4 * 4 + 1][row] = f2b(v.y);
    tile[c4 * 4 + 2][row] = f2b(v.z);
    tile[c4 * 4 + 3][row] = f2b(v.w);
  }
  __syncthreads();
#pragma unroll
  for (int p = 0; p < 4; ++p) {
    int nr = p * 16 + r;
    ushort4 o;
    o.x = tile[nr][c4 * 4 + 0];
    o.y = tile[nr][c4 * 4 + 1];
    o.z = tile[nr][c4 * 4 + 2];
    o.w = tile[nr][c4 * 4 + 3];
    *(ushort4*)(out + (size_t)(n0 + nr) * K + k0 + c4 * 4) = o;
  }
}

__global__ __launch_bounds__(256) void prep_all(
    const float* __restrict__ x, unsigned short* __restrict__ xb, int ncast,
    const float* __restrict__ Wq, unsigned short* __restrict__ WqT,
    const float* __restrict__ Wdown, unsigned short* __restrict__ WdT,
    const float* __restrict__ Wo, unsigned short* __restrict__ WoT,
    const float* __restrict__ Wkup, unsigned short* __restrict__ WkT,
    const float* __restrict__ Wvup, unsigned short* __restrict__ WvT) {
  __shared__ __align__(16) unsigned short tile[64][65];
  const int f = blockIdx.x;
  if (f < 8192) {
    int i = (f * 256 + threadIdx.x) * 4;
    if (i < ncast) {
      float4 v = *(const float4*)(x + i);
      ushort4 o;
      o.x = f2b(v.x); o.y = f2b(v.y); o.z = f2b(v.z); o.w = f2b(v.w);
      *(ushort4*)(xb + i) = o;
    }
  } else if (f < 9216) {
    int l = f - 8192;
    transpose_tile(Wq, WqT, 2048, 2048, l & 31, l >> 5, tile);
  } else if (f < 9472) {
    int l = f - 9216;
    transpose_tile(Wdown, WdT, 2048, 512, l & 7, l >> 3, tile);
  } else if (f < 10496) {
    int l = f - 9472;
    transpose_tile(Wo, WoT, 2048, 2048, l & 31, l >> 5, tile);
  } else if (f < 10752) {
    int l = f - 10496;
    transpose_tile(Wkup, WkT, 512, 2048, l & 31, l >> 5, tile);
  } else {
    int l = f - 10752;
    transpose_tile(Wvup, WvT, 512, 2048, l & 31, l >> 5, tile);
  }
}

// ---------- GEMM v3 ring core: BK=32, 3-buffer ring, counted vmcnt ----------
// v2's one-draining-barrier-per-K-step still waited vmcnt(0) on the JUST-
// issued prefetch (2 buffers = 1 tile in flight = zero slack at the drain).
// Ring of 3 x (8KB A + 8KB B) = 48KB (2 blocks/CU kept) lets tile kt+2 be
// issued at iter kt: the barrier then needs only vmcnt(4) -- waits for the
// tile issued TWO iterations ago (~2 full compute phases of cover), while
// the newest 4 loads float across the barrier (T4, counted vmcnt).
// Cross-wave safety: each wave drains ITS OWN tile-kt loads (vmcnt(4),
// FIFO) before s_barrier => after the barrier every wave's slice of tile
// kt is in LDS. Stage target buf[(kt+2)%3] was read at iter kt-1; all
// waves crossed barrier(kt) since => no overwrite race. Last iter vmcnt(0).
// BK=32 rows are 64B: af/bfr b128 reads hit all 32 banks at the 8-cyc
// minimum -- no swizzle needed (v2's XOR machinery dropped).
__device__ __forceinline__ void gemm_ring3_core(
    const unsigned short* __restrict__ gA, const unsigned short* __restrict__ gB,
    int K, int nk, char* sAb, char* sBb,
    int wave, int quad, int cl, int wm, int wn, f32x4 acc[4][4]) {
  char* a0 = sAb;           char* b0 = sBb;
  char* a1 = sAb + 8192;    char* b1 = sBb + 8192;
  char* a2 = sAb + 16384;   char* b2 = sBb + 16384;
  const int sr = wave * 2048;  // per-wave 32-row slice (32*64B)

  // prologue: stage tile 0 -> buf0, tile 1 -> buf1 (4 loads each per wave)
  async16(gA, a0 + sr);
  async16(gA + (size_t)16 * K, a0 + sr + 1024);
  async16(gB, b0 + sr);
  async16(gB + (size_t)16 * K, b0 + sr + 1024);
  async16(gA + 32, a1 + sr);
  async16(gA + 32 + (size_t)16 * K, a1 + sr + 1024);
  async16(gB + 32, b1 + sr);
  async16(gB + 32 + (size_t)16 * K, b1 + sr + 1024);

  for (int kt = 0; kt < nk; ++kt) {
    // drain own tile-kt loads; let the newest 4 (tile kt+1) float.
    if (kt + 1 < nk)
      asm volatile("s_waitcnt vmcnt(4)" ::: "memory");
    else
      asm volatile("s_waitcnt vmcnt(0)" ::: "memory");
    __builtin_amdgcn_sched_barrier(0);
    __builtin_amdgcn_s_barrier();
    __builtin_amdgcn_sched_barrier(0);

    // issue tile kt+2 into the slot freed at iter kt-1
    if (kt + 2 < nk) {
      const unsigned short* pa = gA + (size_t)(kt + 2) * 32;
      const unsigned short* pb = gB + (size_t)(kt + 2) * 32;
      async16(pa, a2 + sr);
      async16(pa + (size_t)16 * K, a2 + sr + 1024);
      async16(pb, b2 + sr);
      async16(pb + (size_t)16 * K, b2 + sr + 1024);
    }

    // compute tile kt from buf0
    bf16x8 af[4], bfr[4];
#pragma unroll
    for (int i = 0; i < 4; ++i)
      af[i] = *(const bf16x8*)(a0 + (wm + i * 16 + cl) * 64 + quad * 16);
#pragma unroll
    for (int j = 0; j < 4; ++j)
      bfr[j] = *(const bf16x8*)(b0 + (wn + j * 16 + cl) * 64 + quad * 16);
#pragma unroll
    for (int i = 0; i < 4; ++i)
#pragma unroll
      for (int j = 0; j < 4; ++j)
        acc[i][j] = __builtin_amdgcn_mfma_f32_16x16x32_bf16(af[i], bfr[j], acc[i][j], 0, 0, 0);

    // rotate ring: buf0<-buf1, buf1<-buf2, buf2<-old buf0
    char* ta = a0; a0 = a1; a1 = a2; a2 = ta;
    char* tb = b0; b0 = b1; b1 = b2; b2 = tb;
  }
}

// ---------- GEMM: C[M,N] = A[M,K] @ BT[N,K]^T (bf16 in, fp32 accum) ----------
__global__ __launch_bounds__(256) void gemm_bt(
    const unsigned short* __restrict__ A, const unsigned short* __restrict__ BT,
    unsigned short* __restrict__ Cb, float* __restrict__ Cf, int M, int N, int K,
    float cscale) {
  __shared__ __align__(16) char sA[3 * 8192];
  __shared__ __align__(16) char sB[3 * 8192];
  const int tid = threadIdx.x;
  const int wave = tid >> 6, lane = tid & 63;
  const int quad = lane >> 4, cl = lane & 15;
  const int m0 = blockIdx.y * 128, n0 = blockIdx.x * 128;
  const int wm = (wave >> 1) * 64, wn = (wave & 1) * 64;
  (void)M;

  f32x4 acc[4][4] = {};
  const unsigned short* gA = A + (size_t)(m0 + wave * 32 + (lane >> 2)) * K + (lane & 3) * 8;
  const unsigned short* gB = BT + (size_t)(n0 + wave * 32 + (lane >> 2)) * K + (lane & 3) * 8;

  gemm_ring3_core(gA, gB, K, K >> 5, sA, sB, wave, quad, cl, wm, wn, acc);

#pragma unroll
  for (int i = 0; i < 4; ++i)
#pragma unroll
    for (int j = 0; j < 4; ++j)
#pragma unroll
      for (int r = 0; r < 4; ++r) {
        int row = m0 + wm + i * 16 + quad * 4 + r;
        int col = n0 + wn + j * 16 + cl;
        float v = acc[i][j][r];
        if (Cb) Cb[(size_t)row * N + col] = f2b(v * cscale);
        if (Cf) Cf[(size_t)row * N + col] = v;
      }
}

// ---------- fused Q+c projection GEMM (ring-3 body) ----------
__global__ __launch_bounds__(256) void gemm_qc(
    const unsigned short* __restrict__ A, const unsigned short* __restrict__ BT,
    unsigned short* __restrict__ Qb, unsigned short* __restrict__ cb,
    float* __restrict__ cout, int K, float qscale) {
  __shared__ __align__(16) char sA[3 * 8192];
  __shared__ __align__(16) char sB[3 * 8192];
  const int tid = threadIdx.x;
  const int wave = tid >> 6, lane = tid & 63;
  const int quad = lane >> 4, cl = lane & 15;
  const int m0 = blockIdx.y * 128, n0 = blockIdx.x * 128;
  const int wm = (wave >> 1) * 64, wn = (wave & 1) * 64;

  f32x4 acc[4][4] = {};
  const unsigned short* gA = A + (size_t)(m0 + wave * 32 + (lane >> 2)) * K + (lane & 3) * 8;
  const unsigned short* gB = BT + (size_t)(n0 + wave * 32 + (lane >> 2)) * K + (lane & 3) * 8;

  gemm_ring3_core(gA, gB, K, K >> 5, sA, sB, wave, quad, cl, wm, wn, acc);

  const bool qreg = (n0 < 2048);  // block-uniform (2048 % 128 == 0)
#pragma unroll
  for (int i = 0; i < 4; ++i)
#pragma unroll
    for (int j = 0; j < 4; ++j)
#pragma unroll
      for (int r = 0; r < 4; ++r) {
        int row = m0 + wm + i * 16 + quad * 4 + r;
        int col = n0 + wn + j * 16 + cl;
        float v = acc[i][j][r];
        if (qreg) {
          Qb[(size_t)row * 2048 + col] = f2b(v * qscale);
        } else {
          int c2 = col - 2048;
          cb[(size_t)row * 512 + c2] = f2b(v);
          cout[(size_t)row * 512 + c2] = v;
        }
      }
}

// ---------- merged K-proj + V^T-proj (ring-3 body) ----------
// f<512 : Kb[4096,2048] = cb[4096,512] @ WkT[2048,512]^T
// f>=512: VT[2048,4096] = WvT[2048,512] @ cb[4096,512]^T
__global__ __launch_bounds__(256) void gemm_kv(
    const unsigned short* __restrict__ cb, const unsigned short* __restrict__ WkT,
    const unsigned short* __restrict__ WvT, unsigned short* __restrict__ Kb,
    unsigned short* __restrict__ VT) {
  __shared__ __align__(16) char sA[3 * 8192];
  __shared__ __align__(16) char sB[3 * 8192];
  const int tid = threadIdx.x;
  const int wave = tid >> 6, lane = tid & 63;
  const int quad = lane >> 4, cl = lane & 15;
  const int wm = (wave >> 1) * 64, wn = (wave & 1) * 64;
  const int K = 512;

  const unsigned short *A, *BT;
  unsigned short* C;
  int N, m0, n0;
  const int f = blockIdx.x;
  if (f < 512) {
    A = cb; BT = WkT; C = Kb; N = 2048;
    m0 = (f >> 4) * 128; n0 = (f & 15) * 128;
  } else {
    const int g2 = f - 512;
    A = WvT; BT = cb; C = VT; N = 4096;
    m0 = (g2 >> 5) * 128; n0 = (g2 & 31) * 128;
  }

  f32x4 acc[4][4] = {};
  const unsigned short* gA = A + (size_t)(m0 + wave * 32 + (lane >> 2)) * K + (lane & 3) * 8;
  const unsigned short* gB = BT + (size_t)(n0 + wave * 32 + (lane >> 2)) * K + (lane & 3) * 8;

  gemm_ring3_core(gA, gB, K, K >> 5, sA, sB, wave, quad, cl, wm, wn, acc);

#pragma unroll
  for (int i = 0; i < 4; ++i)
#pragma unroll
    for (int j = 0; j < 4; ++j)
#pragma unroll
      for (int r = 0; r < 4; ++r) {
        int row = m0 + wm + i * 16 + quad * 4 + r;
        int col = n0 + wn + j * 16 + cl;
        C[(size_t)row * N + col] = f2b(acc[i][j][r]);
      }
}

// ---------- flash-style causal attention, v6 (R3/R9-exact, 94.5us verified) ----------
// grid (16,16,2), 256 thr, balanced pair {bx, 31-bx} (33 k-tiles/block),
// 56KB LDS -> 2 blocks/CU, sK double-buffered, sVT single + B2, no setprio,
// no XCD remap (R7/R8: remap cut FETCH 10x but halved residency, +40us net).
__global__ __launch_bounds__(256) void mla_attn(
    const unsigned short* __restrict__ Qm, const unsigned short* __restrict__ Km,
    const unsigned short* __restrict__ Vt, unsigned short* __restrict__ Om, int T) {
  const int ld = 2048;
  const int ldv = 4096;  // B*T
  __shared__ __align__(16) unsigned short sK[2][64 * 128];  // [t][d] xor-swizzled
  __shared__ __align__(16) unsigned short sVT[128 * 64];    // [d][t] xor-swizzled
  __shared__ __align__(16) unsigned short sP[64 * 64];      // [q][t] swz(q)-swizzled
  const int h = blockIdx.y, b = blockIdx.z;
  const int tid = threadIdx.x, wave = tid >> 6, lane = tid & 63;
  const int quad = lane >> 4, cl = lane & 15;
  const int nq = T / 64;  // 32

  for (int phase = 0; phase < 2; ++phase) {
    const int qt = phase ? (nq - 1 - blockIdx.x) : blockIdx.x;

    // Q A-fragments in registers (pre-scaled by 1/sqrt(Dh)*log2e in Q-GEMM)
    bf16x8 qf[4];
    {
      const unsigned short* Qg =
          Qm + (size_t)(b * T + qt * 64 + wave * 16 + cl) * ld + h * 128 + quad * 8;
#pragma unroll
      for (int kk = 0; kk < 4; ++kk)
        qf[kk] = *(const bf16x8*)(Qg + kk * 32);
    }

    float m_i[4], l_part[4];
    f32x4 acc_o[8] = {};
#pragma unroll
    for (int r = 0; r < 4; ++r) { m_i[r] = -1e30f; l_part[r] = 0.f; }

    const unsigned short* Kg0 = Km + (size_t)(b * T) * ld + h * 128;
    const unsigned short* Vg0 = Vt + (size_t)(h * 128) * ldv + (size_t)b * T;

    // prologue: stage K[0] into buffer 0
#pragma unroll
    for (int r = 0; r < 4; ++r) {
      int c0 = r * 256 + wave * 64;
      int c = c0 + lane;
      int row = c >> 4, j = (c & 15) ^ (row & 7);
      async16(Kg0 + (size_t)row * ld + j * 8, (char*)sK[0] + c0 * 16);
    }
    __syncthreads();  // drain K[0] (and phase's Q register loads)

    for (int kt = 0; kt <= qt; ++kt) {
      const int cur = kt & 1;
      const char* cK = (const char*)sK[cur];

      // issue next K tile into the other buffer (overlaps QK^T on sK[cur])
      if (kt < qt) {
        const unsigned short* Kg = Kg0 + (size_t)(kt + 1) * 64 * ld;
        char* dK = (char*)sK[cur ^ 1];
#pragma unroll
        for (int r = 0; r < 4; ++r) {
          int c0 = r * 256 + wave * 64;
          int c = c0 + lane;
          int row = c >> 4, j = (c & 15) ^ (row & 7);
          async16(Kg + (size_t)row * ld + j * 8, dK + c0 * 16);
        }
      }
      // issue this tile's V (prev PV reads of sVT completed at B2)
      {
        const unsigned short* Vg = Vg0 + kt * 64;
#pragma unroll
        for (int r = 0; r < 4; ++r) {
          int c0 = r * 256 + wave * 64;
          int c = c0 + lane;
          int d = c >> 3, jv = (c & 7) ^ (d & 7);
          async16(Vg + (size_t)d * ldv + jv * 8, (char*)sVT + c0 * 16);
        }
      }

      // S = Q @ K^T : 16 q-rows (this wave) x 64 keys (exp2 domain, pre-scaled)
      f32x4 s[4] = {};
#pragma unroll
      for (int kk = 0; kk < 4; ++kk) {
#pragma unroll
        for (int j = 0; j < 4; ++j) {
          int t = j * 16 + cl;
          int jp = (kk * 4 + quad) ^ (t & 7);
          bf16x8 bk = *(const bf16x8*)(cK + (t * 16 + jp) * 16);
          s[j] = __builtin_amdgcn_mfma_f32_16x16x32_bf16(qf[kk], bk, s[j], 0, 0, 0);
        }
      }

      // causal mask + online softmax (deferred max, lane-local fast path)
      const bool need_mask = (kt == qt);
#pragma unroll
      for (int r = 0; r < 4; ++r) {
        int q_l = wave * 16 + quad * 4 + r;
        float mxl = -1e30f;
#pragma unroll
        for (int j = 0; j < 4; ++j) {
          float v = s[j][r];
          if (need_mask) {
            int t_l = j * 16 + cl;
            if (t_l > q_l) v = -1e30f;
            s[j][r] = v;
          }
          mxl = fmaxf(mxl, v);
        }
        if (__any(mxl > m_i[r] + 6.f)) {
          float mx = mxl;
#pragma unroll
          for (int off = 1; off < 16; off <<= 1)
            mx = fmaxf(mx, __shfl_xor(mx, off));
          float m_new = fmaxf(m_i[r], mx);
          float alpha = exp2f(m_i[r] - m_new);
          m_i[r] = m_new;
          l_part[r] *= alpha;
#pragma unroll
          for (int jd = 0; jd < 8; ++jd)
            acc_o[jd][r] *= alpha;
        }
        float rs = 0.f;
#pragma unroll
        for (int j = 0; j < 4; ++j) {
          float p = exp2f(s[j][r] - m_i[r]);
          s[j][r] = p;
          rs += p;
        }
        l_part[r] += rs;  // per-lane partial; cross-lane reduce in epilogue
      }

      // write P swizzled into sP (wave-local rows -> no barrier needed)
#pragma unroll
      for (int j = 0; j < 4; ++j)
#pragma unroll
        for (int r = 0; r < 4; ++r) {
          int q = wave * 16 + quad * 4 + r;
          int swz = (q & 7) ^ (((q >> 3) & 1) << 1);
          int t = j * 16 + cl;
          int jp = (t >> 3) ^ swz;
          sP[(q * 8 + jp) * 8 + (t & 7)] = f2b(s[j][r]);
        }

      __syncthreads();  // B1: drains K[kt+1]+V[kt] (covered); sK[cur] reads done

      // O += P @ V (A from own-wave sP rows, B from sVT; both b128)
#pragma unroll
      for (int kk2 = 0; kk2 < 2; ++kk2) {
        int q = wave * 16 + cl;
        int swz = (q & 7) ^ (((q >> 3) & 1) << 1);
        int jp = (kk2 * 4 + quad) ^ swz;
        bf16x8 ap = *(const bf16x8*)((const char*)sP + (q * 8 + jp) * 16);
#pragma unroll
        for (int jd = 0; jd < 8; ++jd) {
          int d = jd * 16 + cl;
          int jpv = (kk2 * 4 + quad) ^ (d & 7);
          bf16x8 bv = *(const bf16x8*)((const char*)sVT + (d * 8 + jpv) * 16);
          acc_o[jd] = __builtin_amdgcn_mfma_f32_16x16x32_bf16(ap, bv, acc_o[jd], 0, 0, 0);
        }
      }

      __syncthreads();  // B2: pure sync — sVT reads done before next V issue
    }

    // epilogue: reduce l partials across the 16 row lanes, normalize, store
#pragma unroll
    for (int r = 0; r < 4; ++r) {
      float l = l_part[r];
#pragma unroll
      for (int off = 1; off < 16; off <<= 1)
        l += __shfl_xor(l, off);
      float inv = 1.f / l;
      int row = b * T + qt * 64 + wave * 16 + quad * 4 + r;
#pragma unroll
      for (int jd = 0; jd < 8; ++jd)
        Om[(size_t)row * ld + h * 128 + jd * 16 + cl] = f2b(acc_o[jd][r] * inv);
    }
  }
}

// ---------- launch ----------
extern "C" void kernel_launch(void* const* d_in, const int* in_sizes, int n_in,
                              void* d_out, int out_size, void* d_ws, size_t ws_size,
                              hipStream_t stream) {
  (void)in_sizes; (void)n_in; (void)out_size; (void)ws_size;
  const int B = 2, T = 2048, Dm = 2048, H = 16, Dh = 128, R = 512;
  const int M = B * T;  // 4096
  const float* x     = (const float*)d_in[0];
  const float* Wq    = (const float*)d_in[1];
  const float* Wdown = (const float*)d_in[2];
  const float* Wkup  = (const float*)d_in[3];
  const float* Wvup  = (const float*)d_in[4];
  const float* Wo    = (const float*)d_in[5];

  float* out  = (float*)d_out;                      // (B*T) x 2048 fp32
  float* cout = out + (size_t)M * Dm;               // (B*T) x 512  fp32

  unsigned short* ws  = (unsigned short*)d_ws;      // bf16 scratch
  unsigned short* WqT = ws;                         // 2048x2048 (stacked B rows 0..2047)
  unsigned short* WdT = WqT + (size_t)Dm * Dm;      // 512x2048  (stacked B rows 2048..2559)
  unsigned short* WoT = WdT + (size_t)R * Dm;       // 2048x2048
  unsigned short* WkT = WoT + (size_t)Dm * Dm;      // 2048x512
  unsigned short* WvT = WkT + (size_t)Dm * R;       // 2048x512
  unsigned short* xb  = WvT + (size_t)Dm * R;       // 4096x2048 (reused as AO)
  unsigned short* cb  = xb + (size_t)M * Dm;        // 4096x512
  unsigned short* Qb  = cb + (size_t)M * R;         // 4096x2048
  unsigned short* Kb  = Qb + (size_t)M * Dm;        // 4096x2048
  unsigned short* VT  = Kb + (size_t)M * Dm;        // 2048x4096 (V^T, d-major)
  unsigned short* AO  = xb;                         // alias: xb dead after Q-proj

  // softmax scale folded into Q: 1/sqrt(128) * log2(e)
  const float qscale = 0.08838834764831845f * 1.4426950408889634f;

  // fused prep: cast + all 5 weight transposes in ONE launch (11008 blocks)
  prep_all<<<11008, 256, 0, stream>>>(x, xb, M * Dm,
                                      Wq, WqT, Wdown, WdT, Wo, WoT,
                                      Wkup, WkT, Wvup, WvT);

  // fused Q + c projection: grid (2560/128, 4096/128) = (20,32) = 640 blocks
  gemm_qc<<<dim3(20, 32), 256, 0, stream>>>(xb, WqT, Qb, cb, cout, Dm, qscale);

  // merged K-proj + V^T-proj: 1024 blocks
  gemm_kv<<<1024, 256, 0, stream>>>(cb, WkT, WvT, Kb, VT);

  // causal attention: balanced pair per block (natural blockIdx mapping)
  mla_attn<<<dim3(T / 128, H, B), 256, 0, stream>>>(Qb, Kb, VT, AO, T);

  // output projection (fp32 out)
  gemm_bt<<<dim3(Dm / 128, M / 128), 256, 0, stream>>>(AO, WoT, nullptr, out, M, Dm, Dm, 1.f);
  (void)Dh; (void)H;
}